// Round 1
// baseline (1695.987 us; speedup 1.0000x reference)
//
#include <hip/hip_runtime.h>
#include <stdint.h>

// ---------------------------------------------------------------------------
// TransformerBlock fused pipeline for MI355X (gfx950), bf16 MFMA path.
//   B=1024, P=9, D=2700, DFF=512.  M = B*P = 9216 rows.
//   N packed = 8192 (q:0..2699, k:2700..5399, v:5400..8099, pad to 8192)
//   K1 padded 2700->2752 (x @ W), K2 = 1024 exactly ([H1|H2] @ [[WC1],[WC2]])
// Round 3: 256x256 8-phase counted-vmcnt GEMM schedule (T2+T3+T4+T5+T1).
//   gemm8_mod : mod = Hb @ WCt^T + bmod  -> MQ (packed bf16)
//   gemm8_main: MQ = (Xb @ Wt^T + bmain) * MQ
// attn_ln unchanged (verified).
// ---------------------------------------------------------------------------

#define MROWS  9216
#define NCOLS  8192
#define KP1    2752
#define KP2    1024
#define DMODEL 2700

typedef __bf16 bf16x8 __attribute__((ext_vector_type(8)));
typedef float  f32x4  __attribute__((ext_vector_type(4)));

__device__ __forceinline__ float b2f(unsigned short u) {
  union { unsigned int u; float f; } v; v.u = ((unsigned int)u) << 16; return v.f;
}
__device__ __forceinline__ unsigned short f2b(float f) {
  union { float f; unsigned int u; } v; v.f = f;
  unsigned int r = v.u + 0x7FFFu + ((v.u >> 16) & 1u);   // RNE
  return (unsigned short)(r >> 16);
}

// async global->LDS, 16B per lane (wave-uniform base + lane*16)
__device__ __forceinline__ void gl2lds16(const void* g, void* l) {
  __builtin_amdgcn_global_load_lds(
      (const __attribute__((address_space(1))) void*)g,
      (__attribute__((address_space(3))) void*)l, 16, 0, 0);
}

// ---------------------------------------------------------------------------
// conversion / packing kernels (unchanged, harness-verified)
// ---------------------------------------------------------------------------

__global__ void cvt_x(const float* __restrict__ src, unsigned short* __restrict__ dst) {
  int idx = blockIdx.x * 256 + threadIdx.x;
  int r = idx / KP1;
  int c = idx - r * KP1;
  float v = (c < DMODEL) ? src[(size_t)r * DMODEL + c] : 0.f;
  dst[idx] = f2b(v);
}

__global__ void cvt_h(const float* __restrict__ H1, const float* __restrict__ H2,
                      unsigned short* __restrict__ dst) {
  int idx = blockIdx.x * 256 + threadIdx.x;
  int r = idx >> 10, c = idx & 1023;
  float v = (c < 512) ? H1[r * 512 + c] : H2[r * 512 + (c - 512)];
  dst[idx] = f2b(v);
}

__global__ void cvt_wqkv(const float* __restrict__ Wq, const float* __restrict__ Wk,
                         const float* __restrict__ Wv, unsigned short* __restrict__ Wt) {
  __shared__ float tile[32][33];
  int k0 = blockIdx.x * 32, n0 = blockIdx.y * 32;
  int tx = threadIdx.x, ty = threadIdx.y;
#pragma unroll
  for (int s = 0; s < 4; s++) {
    int kk = k0 + ty + 8 * s, nn = n0 + tx;
    float v = 0.f;
    if (kk < DMODEL && nn < 3 * DMODEL) {
      int sec = (nn >= 5400) ? 2 : ((nn >= 2700) ? 1 : 0);
      int d = nn - sec * DMODEL;
      const float* W = (sec == 0) ? Wq : ((sec == 1) ? Wk : Wv);
      v = W[(size_t)kk * DMODEL + d];
    }
    tile[ty + 8 * s][tx] = v;
  }
  __syncthreads();
#pragma unroll
  for (int s = 0; s < 4; s++) {
    int nn = n0 + ty + 8 * s, kk = k0 + tx;
    Wt[(size_t)nn * KP1 + kk] = f2b(tile[tx][ty + 8 * s]);
  }
}

__global__ void cvt_wc(const float* __restrict__ C1q, const float* __restrict__ C1k,
                       const float* __restrict__ C1v, const float* __restrict__ C2q,
                       const float* __restrict__ C2k, const float* __restrict__ C2v,
                       unsigned short* __restrict__ Wt) {
  __shared__ float tile[32][33];
  int k0 = blockIdx.x * 32, n0 = blockIdx.y * 32;
  int tx = threadIdx.x, ty = threadIdx.y;
#pragma unroll
  for (int s = 0; s < 4; s++) {
    int kk = k0 + ty + 8 * s, nn = n0 + tx;
    float v = 0.f;
    if (nn < 3 * DMODEL) {
      int sec = (nn >= 5400) ? 2 : ((nn >= 2700) ? 1 : 0);
      int d = nn - sec * DMODEL;
      const float* W;
      int kr = kk;
      if (kk < 512) {
        W = (sec == 0) ? C1q : ((sec == 1) ? C1k : C1v);
      } else {
        W = (sec == 0) ? C2q : ((sec == 1) ? C2k : C2v);
        kr = kk - 512;
      }
      v = W[(size_t)kr * DMODEL + d];
    }
    tile[ty + 8 * s][tx] = v;
  }
  __syncthreads();
#pragma unroll
  for (int s = 0; s < 4; s++) {
    int nn = n0 + ty + 8 * s, kk = k0 + tx;
    Wt[(size_t)nn * KP2 + kk] = f2b(tile[tx][ty + 8 * s]);
  }
}

// ---------------------------------------------------------------------------
// 256x256x(BK=64) 8-phase counted-vmcnt GEMM core.
//   8 waves (2Mx4N), per-wave 128x64 C = acc[8][4] of 16x16 fragments.
//   LDS: 2 buffers x (A 256x64 + B 256x64) bf16 = 128 KiB.
//   Per iteration: consume tile 2j (buf0, phases 1-4) and 2j+1 (buf1, 5-8).
//   Staging: phases 1-4 stage tile 2j+1 -> buf1 (its reads ended last iter);
//            phases 5-8 stage tile 2j+2 -> buf0 (its reads ended at phase 4).
//   Handoff phases (1,5): issue next half-tile FIRST, then vmcnt(2)+barrier
//   (the 8 older loads = incoming tile have landed; 2 newest stay in flight).
//   Frag reuse: quad order (0,0)->(0,1)->(1,1)->(1,0): 28 ds_read_b128/tile.
//   Staging swizzle: phys 16B block (tid&7) at row sr holds k-block
//   (tid&7)^(sr&7); reader kx = (c*4+lq)^l7 (row&7==l7) -- conflict-free,
//   carried over unchanged from the verified round-2 kernel.
// ---------------------------------------------------------------------------

#define BAR() __builtin_amdgcn_s_barrier()

template<int NT, int KS>
__device__ __forceinline__ void gemm8_core(
    unsigned short (&lds)[2][2][16384],
    const unsigned short* __restrict__ Ab,   // per-thread: + (m0+sr)*KS + skb
    const unsigned short* __restrict__ Bb,   // per-thread: + (n0+sr)*KS + skb
    f32x4 (&acc)[8][4],
    int tid, int wm, int wn, int lm, int lq, int l7)
{
  bf16x8 af[2][4], bfr[2][2];

  auto stage = [&](int buf, int op, int h, int t) {
    const unsigned short* s = (op ? Bb : Ab) + (size_t)(h * 128) * KS + (size_t)(t * 64);
    unsigned short* d = &lds[buf][op][h * 128 * 64 + tid * 8];
    gl2lds16(s, d);
    gl2lds16(s + (size_t)64 * KS, d + 4096);
  };
  auto fragsA = [&](int buf, int MH) {
#pragma unroll
    for (int c = 0; c < 2; c++) {
      const int kx = ((c * 4 + lq) ^ l7) * 8;
#pragma unroll
      for (int t = 0; t < 4; t++)
        af[c][t] = *(const bf16x8*)&lds[buf][0][(wm + MH * 64 + t * 16 + lm) * 64 + kx];
    }
  };
  auto fragsB = [&](int buf, int NH) {
#pragma unroll
    for (int c = 0; c < 2; c++) {
      const int kx = ((c * 4 + lq) ^ l7) * 8;
#pragma unroll
      for (int t = 0; t < 2; t++)
        bfr[c][t] = *(const bf16x8*)&lds[buf][1][(wn + (NH * 2 + t) * 16 + lm) * 64 + kx];
    }
  };
  auto mfmas = [&](int MH, int NH) {
    asm volatile("s_waitcnt lgkmcnt(0)" ::: "memory");
    __builtin_amdgcn_sched_barrier(0);
    __builtin_amdgcn_s_setprio(1);
#pragma unroll
    for (int c = 0; c < 2; c++)
#pragma unroll
      for (int mt = 0; mt < 4; mt++)
#pragma unroll
        for (int nt = 0; nt < 2; nt++)
          acc[MH * 4 + mt][NH * 2 + nt] = __builtin_amdgcn_mfma_f32_16x16x32_bf16(
              af[c][mt], bfr[c][nt], acc[MH * 4 + mt][NH * 2 + nt], 0, 0, 0);
    __builtin_amdgcn_s_setprio(0);
  };

  // prologue: tile 0 -> buf0 (8 loads, no wait; phase 1 of j=0 counts them)
  stage(0, 0, 0, 0); stage(0, 0, 1, 0); stage(0, 1, 0, 0); stage(0, 1, 1, 0);

  const int nfull = NT >> 1;
#pragma unroll 1
  for (int j = 0; j < nfull; ++j) {
    const int t1 = 2 * j + 1, t2 = 2 * j + 2;

    // ---- tile 2j in buf0 ----
    stage(1, 0, 0, t1);                                   // ph1: A.h0 of t1
    asm volatile("s_waitcnt vmcnt(2)" ::: "memory");      // tile 2j landed
    BAR();
    fragsA(0, 0); fragsB(0, 0); mfmas(0, 0);
    BAR();

    fragsB(0, 1); stage(1, 0, 1, t1);                     // ph2: A.h1
    BAR();
    mfmas(0, 1);
    BAR();

    fragsA(0, 1); stage(1, 1, 0, t1);                     // ph3: B.h0
    BAR();
    mfmas(1, 1);
    BAR();

    fragsB(0, 0); stage(1, 1, 1, t1);                     // ph4: B.h1
    BAR();
    mfmas(1, 0);
    BAR();

    // ---- tile 2j+1 in buf1 ----
    if (t2 < NT) {
      stage(0, 0, 0, t2);                                 // ph5: A.h0 of t2
      asm volatile("s_waitcnt vmcnt(2)" ::: "memory");    // tile 2j+1 landed
      BAR();
      fragsA(1, 0); fragsB(1, 0); mfmas(0, 0);
      BAR();

      fragsB(1, 1); stage(0, 0, 1, t2);                   // ph6: A.h1
      BAR();
      mfmas(0, 1);
      BAR();

      fragsA(1, 1); stage(0, 1, 0, t2);                   // ph7: B.h0
      BAR();
      mfmas(1, 1);
      BAR();

      fragsB(1, 0); stage(0, 1, 1, t2);                   // ph8: B.h1
      BAR();
      mfmas(1, 0);
      BAR();
    } else {                                              // even-NT tail
      asm volatile("s_waitcnt vmcnt(0)" ::: "memory");
      BAR();
      fragsA(1, 0); fragsB(1, 0); mfmas(0, 0);
      BAR();
      fragsB(1, 1); mfmas(0, 1);
      BAR();
      fragsA(1, 1); mfmas(1, 1);
      BAR();
      fragsB(1, 0); mfmas(1, 0);
      BAR();
    }
  }
  if (NT & 1) {                                           // odd-NT leftover in buf0
    asm volatile("s_waitcnt vmcnt(0)" ::: "memory");
    BAR();
    fragsA(0, 0); fragsB(0, 0); mfmas(0, 0);
    BAR();
    fragsB(0, 1); mfmas(0, 1);
    BAR();
    fragsA(0, 1); mfmas(1, 1);
    BAR();
    fragsB(0, 0); mfmas(1, 0);
    BAR();
  }
}

// modulation GEMM: MQ = packbf16(Hb @ WCt^T + b1 + b2)
__global__ __launch_bounds__(512, 2) void gemm8_mod(
    const unsigned short* __restrict__ Hb, const unsigned short* __restrict__ WCt,
    unsigned short* __restrict__ MQ,
    const float* __restrict__ b1q, const float* __restrict__ b1k, const float* __restrict__ b1v,
    const float* __restrict__ b2q, const float* __restrict__ b2k, const float* __restrict__ b2v)
{
  __shared__ __attribute__((aligned(16))) unsigned short lds[2][2][16384];
  const int tid = threadIdx.x;
  const int wave = tid >> 6, lane = tid & 63;
  const int wm = (wave >> 2) * 128, wn = (wave & 3) * 64;
  const int lm = lane & 15, lq = lane >> 4, l7 = lane & 7;
  const int wg = blockIdx.x;
  const int swz = (wg & 7) * 144 + (wg >> 3);     // 1152 % 8 == 0: bijective
  const int m0 = (swz >> 5) * 256, n0 = (swz & 31) * 256;
  const int sr = tid >> 3;
  const int skb = ((tid & 7) ^ (sr & 7)) * 8;

  const unsigned short* Ab = Hb  + (size_t)(m0 + sr) * KP2 + skb;
  const unsigned short* Bb = WCt + (size_t)(n0 + sr) * KP2 + skb;

  f32x4 acc[8][4];
#pragma unroll
  for (int i = 0; i < 8; i++)
#pragma unroll
    for (int j = 0; j < 4; j++) acc[i][j] = (f32x4){0.f, 0.f, 0.f, 0.f};

  gemm8_core<16, KP2>(lds, Ab, Bb, acc, tid, wm, wn, lm, lq, l7);

  float bmod[4];
#pragma unroll
  for (int nt = 0; nt < 4; nt++) {
    int gc = n0 + wn + nt * 16 + lm;
    float v = 0.f;
    if (gc < 3 * DMODEL) {
      int sec = (gc >= 5400) ? 2 : ((gc >= 2700) ? 1 : 0);
      int d = gc - sec * DMODEL;
      const float* u1 = (sec == 0) ? b1q : ((sec == 1) ? b1k : b1v);
      const float* u2 = (sec == 0) ? b2q : ((sec == 1) ? b2k : b2v);
      v = u1[d] + u2[d];
    }
    bmod[nt] = v;
  }
#pragma unroll
  for (int mt = 0; mt < 8; mt++) {
    int grb = m0 + wm + mt * 16 + lq * 4;       // C/D: col=lane&15, row=quad*4+i
#pragma unroll
    for (int nt = 0; nt < 4; nt++) {
      int gc = n0 + wn + nt * 16 + lm;
#pragma unroll
      for (int i = 0; i < 4; i++)
        MQ[(size_t)(grb + i) * NCOLS + gc] = f2b(acc[mt][nt][i] + bmod[nt]);
    }
  }
}

// main GEMM + fuse: MQ = packbf16((Xb @ Wt^T + b) * MQ)
__global__ __launch_bounds__(512, 2) void gemm8_main(
    const unsigned short* __restrict__ Xb, const unsigned short* __restrict__ Wt,
    unsigned short* MQ,
    const float* __restrict__ bq_, const float* __restrict__ bk_, const float* __restrict__ bv_)
{
  __shared__ __attribute__((aligned(16))) unsigned short lds[2][2][16384];
  const int tid = threadIdx.x;
  const int wave = tid >> 6, lane = tid & 63;
  const int wm = (wave >> 2) * 128, wn = (wave & 3) * 64;
  const int lm = lane & 15, lq = lane >> 4, l7 = lane & 7;
  const int wg = blockIdx.x;
  const int swz = (wg & 7) * 144 + (wg >> 3);
  const int m0 = (swz >> 5) * 256, n0 = (swz & 31) * 256;
  const int sr = tid >> 3;
  const int skb = ((tid & 7) ^ (sr & 7)) * 8;

  const unsigned short* Ab = Xb + (size_t)(m0 + sr) * KP1 + skb;
  const unsigned short* Bb = Wt + (size_t)(n0 + sr) * KP1 + skb;

  f32x4 acc[8][4];
#pragma unroll
  for (int i = 0; i < 8; i++)
#pragma unroll
    for (int j = 0; j < 4; j++) acc[i][j] = (f32x4){0.f, 0.f, 0.f, 0.f};

  gemm8_core<43, KP1>(lds, Ab, Bb, acc, tid, wm, wn, lm, lq, l7);

  float bmain[4];
#pragma unroll
  for (int nt = 0; nt < 4; nt++) {
    int gc = n0 + wn + nt * 16 + lm;
    float v = 0.f;
    if (gc < 3 * DMODEL) {
      int sec = (gc >= 5400) ? 2 : ((gc >= 2700) ? 1 : 0);
      int d = gc - sec * DMODEL;
      const float* bm = (sec == 0) ? bq_ : ((sec == 1) ? bk_ : bv_);
      v = bm[d];
    }
    bmain[nt] = v;
  }
#pragma unroll
  for (int mt = 0; mt < 8; mt++) {
    int grb = m0 + wm + mt * 16 + lq * 4;
#pragma unroll
    for (int nt = 0; nt < 4; nt++) {
      int gc = n0 + wn + nt * 16 + lm;
#pragma unroll
      for (int i = 0; i < 4; i++) {
        size_t off = (size_t)(grb + i) * NCOLS + gc;
        float mod = b2f(MQ[off]);
        MQ[off] = f2b((acc[mt][nt][i] + bmain[nt]) * mod);
      }
    }
  }
}

// ---------------------------------------------------------------------------
// Fused attention (9x9) + softmax + residual + LayerNorm (unchanged, verified)
// ---------------------------------------------------------------------------
__global__ __launch_bounds__(256, 2) void attn_ln(
    const unsigned short* __restrict__ qkv,  // [9216][8192] bf16 (q|k|v packed)
    const float* __restrict__ x,             // [9216][2700] fp32
    const float* __restrict__ gamma, const float* __restrict__ beta,
    float* __restrict__ out)                 // [9216][2700] fp32
{
  __shared__ float part[4][81];
  __shared__ float sc[81];
  __shared__ float redS[4][9], redQ[4][9];
  __shared__ float muL[9], rsL[9];

  const int b = blockIdx.x;
  const int tid = threadIdx.x, wave = tid >> 6, lane = tid & 63;
  const unsigned short* qb = qkv + (size_t)b * 9 * NCOLS;

  // ---- phase 1: scores S[i][j] = q_i . k_j via 16x16x32 MFMA, K-split ----
  {
    const int l15 = lane & 15, lq8 = (lane >> 4) * 8;
    const int rA = (l15 < 9) ? l15 : 8;                 // clamp: rows 9..15 junk
    const unsigned short* qrow = qb + (size_t)rA * NCOLS;          // 16B aligned
    const unsigned short* krow = qb + (size_t)rA * NCOLS + DMODEL; // 8B aligned
    f32x4 accS = (f32x4){0.f, 0.f, 0.f, 0.f};
    for (int s = wave; s < 85; s += 4) {                // 85 = ceil(2700/32)
      int k0 = s * 32 + lq8;
      union { uint2 u[2]; unsigned int w[4]; bf16x8 v; } au, bu;
      au.u[0] = *(const uint2*)(qrow + k0);
      au.u[1] = *(const uint2*)(qrow + k0 + 4);
      bu.u[0] = *(const uint2*)(krow + k0);
      bu.u[1] = *(const uint2*)(krow + k0 + 4);
      if (s == 84) {                                    // mask k >= 2700
#pragma unroll
        for (int wd = 0; wd < 4; wd++)
          if (k0 + 2 * wd >= DMODEL) { au.w[wd] = 0u; bu.w[wd] = 0u; }
      }
      accS = __builtin_amdgcn_mfma_f32_16x16x32_bf16(au.v, bu.v, accS, 0, 0, 0);
    }
#pragma unroll
    for (int i = 0; i < 4; i++) {
      int row = (lane >> 4) * 4 + i, col = l15;
      if (row < 9 && col < 9) part[wave][row * 9 + col] = accS[i];
    }
  }
  __syncthreads();

  if (tid < 81)
    sc[tid] = (part[0][tid] + part[1][tid] + part[2][tid] + part[3][tid])
              * 0.019245008972987526f;                  // 1/sqrt(2700)
  __syncthreads();

  // ---- phase 2: softmax per row (threads 0..8) ----
  if (tid < 9) {
    float mx = -1e30f;
#pragma unroll
    for (int j = 0; j < 9; j++) mx = fmaxf(mx, sc[tid * 9 + j]);
    float e[9], sum = 0.f;
#pragma unroll
    for (int j = 0; j < 9; j++) { e[j] = __expf(sc[tid * 9 + j] - mx); sum += e[j]; }
    float inv = 1.f / sum;
#pragma unroll
    for (int j = 0; j < 9; j++) sc[tid * 9 + j] = e[j] * inv;
  }
  __syncthreads();

  // ---- phase 3: t = x + A.V for all 9 rows, per float4 column-chunk ----
  float sum[9], sq[9];
#pragma unroll
  for (int i = 0; i < 9; i++) { sum[i] = 0.f; sq[i] = 0.f; }
  unsigned int pv[9][3][2];
#pragma unroll
  for (int c = 0; c < 3; c++) {
    int e = tid + c * 256;
    if (e < 675) {                                      // 675 = 2700/4
      float4 t4[9];
#pragma unroll
      for (int i = 0; i < 9; i++)
        t4[i] = ((const float4*)(x + (size_t)(b * 9 + i) * DMODEL))[e];
#pragma unroll
      for (int j = 0; j < 9; j++) {
        ushort4 vv = ((const ushort4*)(qb + (size_t)j * NCOLS + 5400))[e];
        float v0 = b2f(vv.x), v1 = b2f(vv.y), v2 = b2f(vv.z), v3 = b2f(vv.w);
#pragma unroll
        for (int i = 0; i < 9; i++) {
          float p = sc[i * 9 + j];
          t4[i].x += p * v0; t4[i].y += p * v1;
          t4[i].z += p * v2; t4[i].w += p * v3;
        }
      }
#pragma unroll
      for (int i = 0; i < 9; i++) {
        sum[i] += t4[i].x + t4[i].y + t4[i].z + t4[i].w;
        sq[i]  += t4[i].x * t4[i].x + t4[i].y * t4[i].y
                + t4[i].z * t4[i].z + t4[i].w * t4[i].w;
        pv[i][c][0] = (unsigned int)f2b(t4[i].x) | ((unsigned int)f2b(t4[i].y) << 16);
        pv[i][c][1] = (unsigned int)f2b(t4[i].z) | ((unsigned int)f2b(t4[i].w) << 16);
      }
    }
  }

  // ---- phase 4: block reduction for all 9 rows ----
#pragma unroll
  for (int i = 0; i < 9; i++) {
    float s = sum[i], q = sq[i];
#pragma unroll
    for (int off = 32; off > 0; off >>= 1) {
      s += __shfl_down(s, off, 64);
      q += __shfl_down(q, off, 64);
    }
    if (lane == 0) { redS[wave][i] = s; redQ[wave][i] = q; }
  }
  __syncthreads();
  if (tid < 9) {
    float ts = redS[0][tid] + redS[1][tid] + redS[2][tid] + redS[3][tid];
    float tq = redQ[0][tid] + redQ[1][tid] + redQ[2][tid] + redQ[3][tid];
    float mu = ts * (1.f / 2700.f);
    muL[tid] = mu;
    rsL[tid] = rsqrtf(tq * (1.f / 2700.f) - mu * mu + 1e-5f);
  }
  __syncthreads();

  // ---- phase 5: LN write, float4 ----
#pragma unroll
  for (int c = 0; c < 3; c++) {
    int e = tid + c * 256;
    if (e < 675) {
      float4 g = ((const float4*)gamma)[e];
      float4 bb = ((const float4*)beta)[e];
#pragma unroll
      for (int i = 0; i < 9; i++) {
        float m = muL[i], r = rsL[i];
        float t0 = b2f((unsigned short)(pv[i][c][0] & 0xFFFF));
        float t1 = b2f((unsigned short)(pv[i][c][0] >> 16));
        float t2 = b2f((unsigned short)(pv[i][c][1] & 0xFFFF));
        float t3 = b2f((unsigned short)(pv[i][c][1] >> 16));
        float4 o;
        o.x = (t0 - m) * r * g.x + bb.x;
        o.y = (t1 - m) * r * g.y + bb.y;
        o.z = (t2 - m) * r * g.z + bb.z;
        o.w = (t3 - m) * r * g.w + bb.w;
        ((float4*)(out + (size_t)(b * 9 + i) * DMODEL))[e] = o;
      }
    }
  }
}

// ---------------------------------------------------------------------------
extern "C" void kernel_launch(void* const* d_in, const int* in_sizes, int n_in,
                              void* d_out, int out_size, void* d_ws, size_t ws_size,
                              hipStream_t stream) {
  const float* state = (const float*)d_in[0];
  const float* H1    = (const float*)d_in[1];
  const float* H2    = (const float*)d_in[2];
  const float* Wq    = (const float*)d_in[3];
  const float* bq    = (const float*)d_in[4];
  const float* Wk    = (const float*)d_in[5];
  const float* bk    = (const float*)d_in[6];
  const float* Wv    = (const float*)d_in[7];
  const float* bv    = (const float*)d_in[8];
  const float* WC1q  = (const float*)d_in[9];
  const float* bC1q  = (const float*)d_in[10];
  const float* WC1k  = (const float*)d_in[11];
  const float* bC1k  = (const float*)d_in[12];
  const float* WC1v  = (const float*)d_in[13];
  const float* bC1v  = (const float*)d_in[14];
  const float* WC2q  = (const float*)d_in[15];
  const float* bC2q  = (const float*)d_in[16];
  const float* WC2k  = (const float*)d_in[17];
  const float* bC2k  = (const float*)d_in[18];
  const float* WC2v  = (const float*)d_in[19];
  const float* bC2v  = (const float*)d_in[20];
  const float* gamma = (const float*)d_in[21];
  const float* beta  = (const float*)d_in[22];
  float* out = (float*)d_out;

  // workspace layout (256B aligned), total 282,460,160 B
  char* ws = (char*)d_ws;
  unsigned short* Xb  = (unsigned short*)(ws + 0);            // 9216*2752*2
  unsigned short* Wt  = (unsigned short*)(ws + 50724864);     // 8192*2752*2
  unsigned short* Hb  = (unsigned short*)(ws + 95813632);     // 9216*1024*2
  unsigned short* WCt = (unsigned short*)(ws + 114688000);    // 8192*1024*2
  unsigned short* MQ  = (unsigned short*)(ws + 131465216);    // 9216*8192*2

  // 1) convert / pack
  cvt_h<<<dim3(MROWS * KP2 / 256), dim3(256), 0, stream>>>(H1, H2, Hb);
  cvt_wc<<<dim3(KP2 / 32, NCOLS / 32), dim3(32, 8), 0, stream>>>(WC1q, WC1k, WC1v,
                                                                 WC2q, WC2k, WC2v, WCt);
  cvt_x<<<dim3(MROWS * KP1 / 256), dim3(256), 0, stream>>>(state, Xb);
  cvt_wqkv<<<dim3(KP1 / 32, NCOLS / 32), dim3(32, 8), 0, stream>>>(Wq, Wk, Wv, Wt);

  // 2) modulation GEMM (256x256 8-phase): MQ = bf16(Hb@WCt^T + bmod)
  gemm8_mod<<<dim3(MROWS / 256 * NCOLS / 256), dim3(512), 0, stream>>>(
      Hb, WCt, MQ, bC1q, bC1k, bC1v, bC2q, bC2k, bC2v);

  // 3) main GEMM + fuse (256x256 8-phase): MQ = bf16((Xb@Wt^T + b) * MQ)
  gemm8_main<<<dim3(MROWS / 256 * NCOLS / 256), dim3(512), 0, stream>>>(
      Xb, Wt, MQ, bq, bk, bv);

  // 4) attention + softmax + residual + layernorm
  attn_ln<<<dim3(1024), dim3(256), 0, stream>>>(MQ, state, gamma, beta, out);
}